// Round 5
// baseline (232.368 us; speedup 1.0000x reference)
//
#include <hip/hip_runtime.h>
#include <hip/hip_bf16.h>

// Problem constants
#define BB 32
#define DD 64
#define HW 1024
#define NN 32768   // BB*HW
#define MM 1024

typedef _Float16 half8 __attribute__((ext_vector_type(8)));
typedef float    floatx4 __attribute__((ext_vector_type(4)));

#define MFMA16(a, b, c) __builtin_amdgcn_mfma_f32_16x16x32_f16((a), (b), (c), 0, 0, 0)

// lo-term scaling to dodge fp16-denormal flush in the MFMA pipe
#define LO_SCALE   2048.0f
#define LO_INV     (1.0f / 2048.0f)

// ---------------------------------------------------------------------------
// Kernel 1 (prep): swizzle -2*codebook into MFMA B-frag order (fp16 hi/lo),
// compute codebook squared norms, zero the loss slot.  16 blocks x 512.
// B frag for mfma_f32_16x16x32_f16: B[k][n]: n=lane&15, k=(lane>>4)*8+j.
// Storage (half8 units): ch8[(mtile*2+kstep)*64 + lane]; cl = lo * 2048.
// ---------------------------------------------------------------------------
__global__ void k_prep(const float* __restrict__ cb,
                       _Float16* __restrict__ ch,
                       _Float16* __restrict__ cl,
                       float* __restrict__ y2,
                       float* __restrict__ loss_slot) {
    int u = blockIdx.x * blockDim.x + threadIdx.x;   // 0..8191
    if (u == 0) *loss_slot = 0.0f;

    if (u < 64 * 2 * 64) {
        int lane  = u & 63;
        int kstep = (u >> 6) & 1;
        int mtile = u >> 7;
        int m  = mtile * 16 + (lane & 15);
        int d0 = kstep * 32 + ((lane >> 4) & 3) * 8;
        const float* src = cb + (size_t)m * DD + d0;
        half8 h, l;
#pragma unroll
        for (int j = 0; j < 8; ++j) {
            float x = -2.0f * src[j];
            _Float16 hi = (_Float16)x;
            _Float16 lo = (_Float16)((x - (float)hi) * LO_SCALE);
            h[j] = hi;
            l[j] = lo;
        }
        *(half8*)(ch + (size_t)u * 8) = h;
        *(half8*)(cl + (size_t)u * 8) = l;
    }

    if (u < MM) {
        const float4* c4 = (const float4*)(cb + (size_t)u * DD);
        float s = 0.f;
#pragma unroll
        for (int k = 0; k < 16; ++k) {
            float4 v = c4[k];
            s += v.x * v.x + v.y * v.y + v.z * v.z + v.w * v.w;
        }
        y2[u] = s;
    }
}

// ---------------------------------------------------------------------------
// Kernel 2 (main): fused distance + argmin + q_error + z_q + loss.
// 512 blocks x 512 threads (8 waves), 2 blocks/CU (LDS ~77KB, VGPR<=128).
// Block = 64 rows.  B streamed global -> LDS (double-buffered 4-mtile chunks,
// 16KB each, 2 staging half8/thread), waves read frags via ds_read_b128.
// Wave w: row-half rh = w>>2 (2 ntiles), mtile-in-chunk mi = w&3.
// 16 chunks x (4 ds_read_b128 + 12 MFMA) per wave; one barrier per chunk.
// Numerics: identical 6-MFMA sequence / scan order as rounds 1-4 ->
// bit-identical ind/dmin/z_q.
// ---------------------------------------------------------------------------
__global__ __launch_bounds__(512, 4) void k_main(const float* __restrict__ z,
                                                 const float* __restrict__ noise,
                                                 const _Float16* __restrict__ ch,
                                                 const _Float16* __restrict__ cl,
                                                 const float* __restrict__ y2,
                                                 float* __restrict__ zq,
                                                 float* __restrict__ ind_out,
                                                 float* __restrict__ loss_slot) {
    __shared__ float zt[64][65];     // zt[row(hw)][d]
    __shared__ float nt[64][65];     // nt[d][row(hw)]
    __shared__ float y2s[MM];
    __shared__ float x2p[64][8];
    __shared__ float snorm[64];
    __shared__ float scale_s[64];
    __shared__ float bestv_s[4][64]; // [code-group(mi)][row]
    __shared__ int   besti_s[4][64];
    __shared__ float partials[512];
    __shared__ float sq[4];
    __shared__ _Float16 bufB[2 * 8192];   // 2 x 16KB chunk buffers

    const int t    = threadIdx.x;
    const int lane = t & 63;
    const int wv   = t >> 6;            // wave 0..7
    const int mi   = wv & 3;            // mtile-in-chunk
    const int rh   = wv >> 2;           // row half
    const int quad = lane >> 4;         // 0..3
    const int col  = lane & 15;         // 0..15
    const int blk  = blockIdx.x;        // 0..511
    const int b    = blk >> 4;
    const int hw0  = (blk & 15) << 6;

    const half8* ch8 = (const half8*)ch;
    const half8* cl8 = (const half8*)cl;
    half8* bh8 = (half8*)bufB;

    // per-thread staging constants: element e = q*512 + t  (q = 0,1)
    // region r = e>>6 (1KB units), j = e&63; ty = r&1 picks ch/cl;
    // global half8 idx = c*512 + (r>>1)*64 + j ; LDS half8 idx = (bi<<10)+e.
    const int e0 = t, e1 = 512 + t;
    const int r0 = e0 >> 6, j0 = e0 & 63;
    const int r1 = e1 >> 6, j1 = e1 & 63;
    const half8* s0base = ((r0 & 1) ? cl8 : ch8) + ((r0 >> 1) << 6) + j0;
    const half8* s1base = ((r1 & 1) ? cl8 : ch8) + ((r1 >> 1) << 6) + j1;

    half8 st0[2], st1[2];   // staging regs, parity = chunk&1

    // issue chunk-0 loads first (deep in the vmcnt queue)
    st0[0] = s0base[0];
    st1[0] = s1base[0];

    const float* zbase = z + ((size_t)b << 16) + hw0;

    // ---- stage z tile (coalesced), y2, noise tile (+ row norms) ----
    for (int i = t; i < 64 * 64; i += 512) {
        int d = i >> 6, r = i & 63;
        zt[r][d] = zbase[(size_t)d * HW + r];
    }
    for (int i = t; i < MM; i += 512) y2s[i] = y2[i];

    {
        const float4* noise4 = (const float4*)noise;
        const size_t base4 = (size_t)blk * 1024;     // 4096 floats / 4
#pragma unroll
        for (int k = 0; k < 2; ++k) {
            int v = t + 512 * k;                     // float4 index [0,1024)
            float4 vv = noise4[base4 + v];
            int c  = v >> 4;
            int d0 = (v & 15) << 2;
            nt[d0 + 0][c] = vv.x;
            nt[d0 + 1][c] = vv.y;
            nt[d0 + 2][c] = vv.z;
            nt[d0 + 3][c] = vv.w;
            float p = vv.x * vv.x + vv.y * vv.y + vv.z * vv.z + vv.w * vv.w;
            p += __shfl_xor(p, 1);
            p += __shfl_xor(p, 2);
            p += __shfl_xor(p, 4);
            p += __shfl_xor(p, 8);
            if ((t & 15) == 0) snorm[c] = p;
        }
    }
    __syncthreads();

    // ---- x2 partials + resident A fragments (hi/lo fp16), 2 ntiles ----
    {
        int row = t & 63, seg = t >> 6;
        float s = 0.f;
#pragma unroll
        for (int j = 0; j < 8; ++j) {
            float v = zt[row][seg * 8 + j];
            s = __builtin_fmaf(v, v, s);
        }
        x2p[row][seg] = s;
    }

    // A frag: A[m][k]: m=lane&15, k=(lane>>4)*8+j.
    half8 ah[2][2], al[2][2];
#pragma unroll
    for (int n2 = 0; n2 < 2; ++n2) {
        int row = rh * 32 + n2 * 16 + col;
#pragma unroll
        for (int ks = 0; ks < 2; ++ks) {
            int d0 = ks * 32 + quad * 8;
            half8 h, l;
#pragma unroll
            for (int j = 0; j < 8; ++j) {
                float x = zt[row][d0 + j];
                _Float16 hi = (_Float16)x;
                _Float16 lo = (_Float16)((x - (float)hi) * LO_SCALE);
                h[j] = hi;
                l[j] = lo;
            }
            ah[n2][ks] = h;
            al[n2][ks] = l;
        }
    }

    // write chunk 0 to LDS buffer 0, issue chunk-1 loads
    bh8[e0] = st0[0];
    bh8[e1] = st1[0];
    st0[1] = s0base[512];
    st1[1] = s1base[512];
    __syncthreads();

    // ---- main loop: 16 chunks, double-buffered through LDS ----
    float best[8];
    int   bmt[8];
#pragma unroll
    for (int s = 0; s < 8; ++s) { best[s] = 1e30f; bmt[s] = 0; }

#pragma unroll
    for (int c = 0; c < 16; ++c) {
        const int bi = c & 1;
        // B frags for this wave's mtile from LDS (region = mi*4 + ks*2 + ty)
        const half8* bb = bh8 + (bi << 10);
        half8 h0 = bb[(((mi << 2) + 0) << 6) + lane];
        half8 l0 = bb[(((mi << 2) + 1) << 6) + lane];
        half8 h1 = bb[(((mi << 2) + 2) << 6) + lane];
        half8 l1 = bb[(((mi << 2) + 3) << 6) + lane];

        const int mt = c * 4 + mi;
        float y2v = y2s[(mt << 4) + col];
        floatx4 a1[2], a2[2];
#pragma unroll
        for (int n2 = 0; n2 < 2; ++n2) {
            floatx4 i1 = {y2v, y2v, y2v, y2v};
            floatx4 i2 = {0.f, 0.f, 0.f, 0.f};
            a1[n2] = i1;
            a2[n2] = i2;
        }
#pragma unroll
        for (int n2 = 0; n2 < 2; ++n2) {
            a1[n2] = MFMA16(ah[n2][0], h0, a1[n2]);   // hi*hi (k 0..31)
            a2[n2] = MFMA16(al[n2][0], h0, a2[n2]);   // lo*hi
            a2[n2] = MFMA16(ah[n2][0], l0, a2[n2]);   // hi*lo
            a1[n2] = MFMA16(ah[n2][1], h1, a1[n2]);   // hi*hi (k 32..63)
            a2[n2] = MFMA16(al[n2][1], h1, a2[n2]);
            a2[n2] = MFMA16(ah[n2][1], l1, a2[n2]);
        }
#pragma unroll
        for (int n2 = 0; n2 < 2; ++n2) {
#pragma unroll
            for (int r = 0; r < 4; ++r) {
                float v = __builtin_fmaf(a2[n2][r], LO_INV, a1[n2][r]);
                int s = n2 * 4 + r;
                bool cc = v < best[s];
                best[s] = cc ? v : best[s];
                bmt[s]  = cc ? mt : bmt[s];
            }
        }

        // pipeline: write chunk c+1 (already in regs) to the other buffer,
        // then issue global loads for chunk c+2 into the freed reg set.
        if (c < 15) {
            const int pnext = (c + 1) & 1;
            bh8[(pnext << 10) + e0] = st0[pnext];
            bh8[(pnext << 10) + e1] = st1[pnext];
            if (c < 14) {
                const int pn2 = (c + 2) & 1;
                st0[pn2] = s0base[(c + 2) << 9];
                st1[pn2] = s1base[(c + 2) << 9];
            }
        }
        __syncthreads();
    }

    // ---- per-wave cross-lane argmin (16 lanes share a row), then LDS ----
#pragma unroll
    for (int n2 = 0; n2 < 2; ++n2) {
#pragma unroll
        for (int r = 0; r < 4; ++r) {
            int s = n2 * 4 + r;
            float v  = best[s];
            int  idx = bmt[s] * 16 + col;
#pragma unroll
            for (int mask = 1; mask <= 8; mask <<= 1) {
                float v2 = __shfl_xor(v, mask);
                int   i2 = __shfl_xor(idx, mask);
                if (v2 < v || (v2 == v && i2 < idx)) { v = v2; idx = i2; }
            }
            if (col == 0) {
                int rl = rh * 32 + n2 * 16 + quad * 4 + r;
                bestv_s[mi][rl] = v;
                besti_s[mi][rl] = idx;
            }
        }
    }
    __syncthreads();

    // ---- merge code-groups; write ind; compute scale in LDS ----
    if (t < 64) {
        float bv = bestv_s[0][t];
        int   bi = besti_s[0][t];
#pragma unroll
        for (int w = 1; w < 4; ++w) {
            float v = bestv_s[w][t];
            int   ix = besti_s[w][t];
            if (v < bv || (v == bv && ix < bi)) { bv = v; bi = ix; }
        }
        float x2 = 0.f;
#pragma unroll
        for (int s = 0; s < 8; ++s) x2 += x2p[t][s];
        float dm = x2 + bv;
        int n = (blk << 6) + t;
        ind_out[n] = (float)bi;
        float nr = fmaxf(sqrtf(snorm[t]), 1e-9f);
        scale_s[t] = sqrtf(fmaxf(dm, 0.f)) / nr;
    }
    __syncthreads();

    // ---- z_q write (coalesced, z from LDS) + loss partials ----
    float acc = 0.f;
    const size_t obase = ((size_t)b << 16) + hw0;
#pragma unroll
    for (int it = 0; it < 8; ++it) {
        int flat = it * 512 + t;
        int d = flat >> 6;               // wave-uniform
        int c = t & 63;
        float v = zt[c][d] + nt[d][c] * scale_s[c];
        zq[obase + (size_t)d * HW + c] = v;
        acc += v;
    }

    partials[t] = acc;
    __syncthreads();
    if (t < 4) {
        float s = 0.f;
        for (int g = 0; g < 8; ++g)
            for (int j = 0; j < 16; ++j)
                s += partials[g * 64 + t * 16 + j];
        sq[t] = s * s;
    }
    __syncthreads();
    if (t == 0) {
        float contrib = (sq[0] + sq[1] + sq[2] + sq[3]) * (1.0f / 33554432.0f);
        atomicAdd(loss_slot, contrib);
    }
}

// ---------------------------------------------------------------------------
extern "C" void kernel_launch(void* const* d_in, const int* in_sizes, int n_in,
                              void* d_out, int out_size, void* d_ws, size_t ws_size,
                              hipStream_t stream) {
    const float* z        = (const float*)d_in[0];   // (32,64,32,32)
    const float* codebook = (const float*)d_in[1];   // (1024,64)
    const float* noise    = (const float*)d_in[2];   // (32768,64)

    float* out      = (float*)d_out;
    float* zq_out   = out;                 // 2097152 floats
    float* loss_ptr = out + 2097152;       // 1 float
    float* ind_out  = out + 2097153;       // 32768 floats

    float* y2       = (float*)d_ws;             // 1024 floats
    _Float16* ch    = (_Float16*)(y2 + MM);     // 65536 halves (128KB)
    _Float16* cl    = ch + 65536;               // 65536 halves (128KB)

    k_prep<<<16,  512, 0, stream>>>(codebook, ch, cl, y2, loss_ptr);
    k_main<<<512, 512, 0, stream>>>(z, noise, ch, cl, y2,
                                    zq_out, ind_out, loss_ptr);
}

// Round 6
// 129.807 us; speedup vs baseline: 1.7901x; 1.7901x over previous
//
#include <hip/hip_runtime.h>
#include <hip/hip_bf16.h>

// Problem constants
#define BB 32
#define DD 64
#define HW 1024
#define NN 32768   // BB*HW
#define MM 1024

typedef _Float16 half8 __attribute__((ext_vector_type(8)));
typedef float    floatx4 __attribute__((ext_vector_type(4)));

#define MFMA16(a, b, c) __builtin_amdgcn_mfma_f32_16x16x32_f16((a), (b), (c), 0, 0, 0)

// lo-term scaling to dodge fp16-denormal flush in the MFMA pipe
#define LO_SCALE   2048.0f
#define LO_INV     (1.0f / 2048.0f)

// ---------------------------------------------------------------------------
// Kernel 1 (prep): swizzle -2*codebook into MFMA B-frag order (fp16 hi/lo),
// compute codebook squared norms, zero the loss slot.  16 blocks x 512.
// B frag for mfma_f32_16x16x32_f16: B[k][n]: n=lane&15, k=(lane>>4)*8+j.
// Storage (half8 units): ch8[(mtile*2+kstep)*64 + lane]; cl = lo * 2048.
// ---------------------------------------------------------------------------
__global__ void k_prep(const float* __restrict__ cb,
                       _Float16* __restrict__ ch,
                       _Float16* __restrict__ cl,
                       float* __restrict__ y2,
                       float* __restrict__ loss_slot) {
    int u = blockIdx.x * blockDim.x + threadIdx.x;   // 0..8191
    if (u == 0) *loss_slot = 0.0f;

    if (u < 64 * 2 * 64) {
        int lane  = u & 63;
        int kstep = (u >> 6) & 1;
        int mtile = u >> 7;
        int m  = mtile * 16 + (lane & 15);
        int d0 = kstep * 32 + ((lane >> 4) & 3) * 8;
        const float* src = cb + (size_t)m * DD + d0;
        half8 h, l;
#pragma unroll
        for (int j = 0; j < 8; ++j) {
            float x = -2.0f * src[j];
            _Float16 hi = (_Float16)x;
            _Float16 lo = (_Float16)((x - (float)hi) * LO_SCALE);
            h[j] = hi;
            l[j] = lo;
        }
        *(half8*)(ch + (size_t)u * 8) = h;
        *(half8*)(cl + (size_t)u * 8) = l;
    }

    if (u < MM) {
        const float4* c4 = (const float4*)(cb + (size_t)u * DD);
        float s = 0.f;
#pragma unroll
        for (int k = 0; k < 16; ++k) {
            float4 v = c4[k];
            s += v.x * v.x + v.y * v.y + v.z * v.z + v.w * v.w;
        }
        y2[u] = s;
    }
}

// ---------------------------------------------------------------------------
// Kernel 2 (main): fused distance + argmin + q_error + z_q + loss.
// 512 blocks x 512 threads (8 waves).  Block = 64 rows (b = blk>>4,
// hw0 = (blk&15)<<6).  Wave w: row-half nth = w&1 (2 ntiles = 32 rows),
// code-quarter cq = w>>1 (16 mtiles = 256 codes).
// A frags resident in regs (32 VGPRs); B frags streamed global->VGPR,
// 1-deep register double-buffer, fully unrolled (~110 live VGPRs, NO
// launch_bounds min-waves cap -- r4/r5 showed any cap triggers scratch
// spills that cost 3-5x; allocator must stay free).
// acc1 = y2 + hi*hi ; acc2 = 2048*(hi*lo+lo*hi);
// dist_partial = acc1 + acc2/2048 (x2 added at epilogue, argmin-invariant).
// Same per-(row,code) MFMA sequence / merge order as all passing rounds ->
// bit-identical ind/dmin/z_q.
// ---------------------------------------------------------------------------
__global__ __launch_bounds__(512) void k_main(const float* __restrict__ z,
                                              const float* __restrict__ noise,
                                              const _Float16* __restrict__ ch,
                                              const _Float16* __restrict__ cl,
                                              const float* __restrict__ y2,
                                              float* __restrict__ zq,
                                              float* __restrict__ ind_out,
                                              float* __restrict__ loss_slot) {
    __shared__ float zt[64][65];     // zt[row(hw)][d]
    __shared__ float nt[64][65];     // nt[d][row(hw)]
    __shared__ float y2s[MM];
    __shared__ float x2p[64][8];
    __shared__ float snorm[64];
    __shared__ float scale_s[64];
    __shared__ float bestv_s[4][64]; // [code-quarter][row]
    __shared__ int   besti_s[4][64];
    __shared__ float partials[512];
    __shared__ float sq[4];

    const int t    = threadIdx.x;
    const int lane = t & 63;
    const int wv   = t >> 6;            // wave 0..7
    const int nth  = wv & 1;            // row half
    const int cq   = wv >> 1;           // code quarter
    const int quad = lane >> 4;         // 0..3
    const int col  = lane & 15;         // 0..15
    const int blk  = blockIdx.x;        // 0..511
    const int b    = blk >> 4;
    const int hw0  = (blk & 15) << 6;

    const float* zbase = z + ((size_t)b << 16) + hw0;

    // ---- stage z tile (coalesced), y2, noise tile (+ row norms) ----
    for (int i = t; i < 64 * 64; i += 512) {
        int d = i >> 6, r = i & 63;
        zt[r][d] = zbase[(size_t)d * HW + r];
    }
    for (int i = t; i < MM; i += 512) y2s[i] = y2[i];

    {
        const float4* noise4 = (const float4*)noise;
        const size_t base4 = (size_t)blk * 1024;     // 4096 floats / 4
#pragma unroll
        for (int k = 0; k < 2; ++k) {
            int v = t + 512 * k;                     // float4 index [0,1024)
            float4 vv = noise4[base4 + v];
            int c  = v >> 4;
            int d0 = (v & 15) << 2;
            nt[d0 + 0][c] = vv.x;
            nt[d0 + 1][c] = vv.y;
            nt[d0 + 2][c] = vv.z;
            nt[d0 + 3][c] = vv.w;
            float p = vv.x * vv.x + vv.y * vv.y + vv.z * vv.z + vv.w * vv.w;
            p += __shfl_xor(p, 1);
            p += __shfl_xor(p, 2);
            p += __shfl_xor(p, 4);
            p += __shfl_xor(p, 8);
            if ((t & 15) == 0) snorm[c] = p;
        }
    }
    __syncthreads();

    // ---- x2 partials + resident A fragments (hi/lo fp16) ----
    {
        int row = t & 63, seg = t >> 6;
        float s = 0.f;
#pragma unroll
        for (int j = 0; j < 8; ++j) {
            float v = zt[row][seg * 8 + j];
            s = __builtin_fmaf(v, v, s);
        }
        x2p[row][seg] = s;
    }

    // A frag: A[m][k]: m=lane&15, k=(lane>>4)*8+j.  2 ntiles of 16 rows.
    half8 ah[2][2], al[2][2];
#pragma unroll
    for (int nt2 = 0; nt2 < 2; ++nt2) {
        int row = nth * 32 + nt2 * 16 + col;
#pragma unroll
        for (int ks = 0; ks < 2; ++ks) {
            int d0 = ks * 32 + quad * 8;
            half8 h, l;
#pragma unroll
            for (int j = 0; j < 8; ++j) {
                float x = zt[row][d0 + j];
                _Float16 hi = (_Float16)x;
                _Float16 lo = (_Float16)((x - (float)hi) * LO_SCALE);
                h[j] = hi;
                l[j] = lo;
            }
            ah[nt2][ks] = h;
            al[nt2][ks] = l;
        }
    }
    __syncthreads();

    // ---- main loop: 16 mtiles per wave, reg double-buffer, full unroll ----
    const half8* ch8 = (const half8*)ch;
    const half8* cl8 = (const half8*)cl;

    float best[8];
    int   bmt[8];
#pragma unroll
    for (int s = 0; s < 8; ++s) { best[s] = 1e30f; bmt[s] = 0; }

    const int mt0 = cq * 16;
    half8 bh0 = ch8[((mt0 * 2 + 0) << 6) + lane];
    half8 bl0 = cl8[((mt0 * 2 + 0) << 6) + lane];
    half8 bh1 = ch8[((mt0 * 2 + 1) << 6) + lane];
    half8 bl1 = cl8[((mt0 * 2 + 1) << 6) + lane];

#pragma unroll
    for (int i = 0; i < 16; ++i) {
        const int mt  = mt0 + i;
        const int mtn = mt + (i < 15 ? 1 : 0);
        half8 nh0 = ch8[((mtn * 2 + 0) << 6) + lane];
        half8 nl0 = cl8[((mtn * 2 + 0) << 6) + lane];
        half8 nh1 = ch8[((mtn * 2 + 1) << 6) + lane];
        half8 nl1 = cl8[((mtn * 2 + 1) << 6) + lane];

        float y2v = y2s[(mt << 4) + col];
        floatx4 a1[2], a2[2];
#pragma unroll
        for (int n2 = 0; n2 < 2; ++n2) {
            floatx4 i1 = {y2v, y2v, y2v, y2v};
            floatx4 i2 = {0.f, 0.f, 0.f, 0.f};
            a1[n2] = i1;
            a2[n2] = i2;
        }
#pragma unroll
        for (int n2 = 0; n2 < 2; ++n2) {
            a1[n2] = MFMA16(ah[n2][0], bh0, a1[n2]);   // hi*hi (k 0..31)
            a2[n2] = MFMA16(al[n2][0], bh0, a2[n2]);   // lo*hi
            a2[n2] = MFMA16(ah[n2][0], bl0, a2[n2]);   // hi*lo
            a1[n2] = MFMA16(ah[n2][1], bh1, a1[n2]);   // hi*hi (k 32..63)
            a2[n2] = MFMA16(al[n2][1], bh1, a2[n2]);
            a2[n2] = MFMA16(ah[n2][1], bl1, a2[n2]);
        }
#pragma unroll
        for (int n2 = 0; n2 < 2; ++n2) {
#pragma unroll
            for (int r = 0; r < 4; ++r) {
                float v = __builtin_fmaf(a2[n2][r], LO_INV, a1[n2][r]);
                int s = n2 * 4 + r;
                bool c = v < best[s];
                best[s] = c ? v : best[s];
                bmt[s]  = c ? mt : bmt[s];
            }
        }
        bh0 = nh0; bl0 = nl0; bh1 = nh1; bl1 = nl1;
    }

    // ---- per-wave cross-lane argmin (16 lanes share a row), then LDS ----
#pragma unroll
    for (int n2 = 0; n2 < 2; ++n2) {
#pragma unroll
        for (int r = 0; r < 4; ++r) {
            int s = n2 * 4 + r;
            float v  = best[s];
            int  idx = bmt[s] * 16 + col;
#pragma unroll
            for (int mask = 1; mask <= 8; mask <<= 1) {
                float v2 = __shfl_xor(v, mask);
                int   i2 = __shfl_xor(idx, mask);
                if (v2 < v || (v2 == v && i2 < idx)) { v = v2; idx = i2; }
            }
            if (col == 0) {
                int rl = nth * 32 + n2 * 16 + quad * 4 + r;
                bestv_s[cq][rl] = v;
                besti_s[cq][rl] = idx;
            }
        }
    }
    __syncthreads();

    // ---- merge code-quarters; write ind; compute scale in LDS ----
    if (t < 64) {
        float bv = bestv_s[0][t];
        int   bi = besti_s[0][t];
#pragma unroll
        for (int w = 1; w < 4; ++w) {
            float v = bestv_s[w][t];
            int   ix = besti_s[w][t];
            if (v < bv || (v == bv && ix < bi)) { bv = v; bi = ix; }
        }
        float x2 = 0.f;
#pragma unroll
        for (int s = 0; s < 8; ++s) x2 += x2p[t][s];
        float dm = x2 + bv;
        int n = (blk << 6) + t;
        ind_out[n] = (float)bi;
        float nr = fmaxf(sqrtf(snorm[t]), 1e-9f);
        scale_s[t] = sqrtf(fmaxf(dm, 0.f)) / nr;
    }
    __syncthreads();

    // ---- z_q write (coalesced, z from LDS) + loss partials ----
    float acc = 0.f;
    const size_t obase = ((size_t)b << 16) + hw0;
#pragma unroll
    for (int it = 0; it < 8; ++it) {
        int flat = it * 512 + t;
        int d = flat >> 6;               // wave-uniform
        int c = t & 63;
        float v = zt[c][d] + nt[d][c] * scale_s[c];
        zq[obase + (size_t)d * HW + c] = v;
        acc += v;
    }

    partials[t] = acc;
    __syncthreads();
    if (t < 4) {
        float s = 0.f;
        for (int g = 0; g < 8; ++g)
            for (int j = 0; j < 16; ++j)
                s += partials[g * 64 + t * 16 + j];
        sq[t] = s * s;
    }
    __syncthreads();
    if (t == 0) {
        float contrib = (sq[0] + sq[1] + sq[2] + sq[3]) * (1.0f / 33554432.0f);
        atomicAdd(loss_slot, contrib);
    }
}

// ---------------------------------------------------------------------------
extern "C" void kernel_launch(void* const* d_in, const int* in_sizes, int n_in,
                              void* d_out, int out_size, void* d_ws, size_t ws_size,
                              hipStream_t stream) {
    const float* z        = (const float*)d_in[0];   // (32,64,32,32)
    const float* codebook = (const float*)d_in[1];   // (1024,64)
    const float* noise    = (const float*)d_in[2];   // (32768,64)

    float* out      = (float*)d_out;
    float* zq_out   = out;                 // 2097152 floats
    float* loss_ptr = out + 2097152;       // 1 float
    float* ind_out  = out + 2097153;       // 32768 floats

    float* y2       = (float*)d_ws;             // 1024 floats
    _Float16* ch    = (_Float16*)(y2 + MM);     // 65536 halves (128KB)
    _Float16* cl    = ch + 65536;               // 65536 halves (128KB)

    k_prep<<<16,  512, 0, stream>>>(codebook, ch, cl, y2, loss_ptr);
    k_main<<<512, 512, 0, stream>>>(z, noise, ch, cl, y2,
                                    zq_out, ind_out, loss_ptr);
}

// Round 7
// 99.945 us; speedup vs baseline: 2.3250x; 1.2988x over previous
//
#include <hip/hip_runtime.h>
#include <hip/hip_bf16.h>

// Problem constants
#define BB 32
#define DD 64
#define HW 1024
#define NN 32768   // BB*HW
#define MM 1024

typedef _Float16 half8 __attribute__((ext_vector_type(8)));
typedef float    floatx4 __attribute__((ext_vector_type(4)));

#define MFMA16(a, b, c) __builtin_amdgcn_mfma_f32_16x16x32_f16((a), (b), (c), 0, 0, 0)

// lo-term scaling to dodge fp16-denormal flush in the MFMA pipe
#define LO_SCALE   2048.0f
#define LO_INV     (1.0f / 2048.0f)

// async global->LDS copy, 16B per lane; LDS dest = wave-uniform base + lane*16
typedef __attribute__((address_space(1))) const void* gas_t;
typedef __attribute__((address_space(3)))       void* las_t;
#define ASYNC16(g, l) __builtin_amdgcn_global_load_lds((gas_t)(g), (las_t)(l), 16, 0, 0)

// ---------------------------------------------------------------------------
// Kernel 1 (prep): swizzle -2*codebook into MFMA B-frag order (fp16 hi/lo),
// compute codebook squared norms, zero the loss slot.  16 blocks x 512.
// B frag for mfma_f32_16x16x32_f16: B[k][n]: n=lane&15, k=(lane>>4)*8+j.
// Storage (half8 units): ch8[(mtile*2+kstep)*64 + lane]; cl = lo * 2048.
// ---------------------------------------------------------------------------
__global__ void k_prep(const float* __restrict__ cb,
                       _Float16* __restrict__ ch,
                       _Float16* __restrict__ cl,
                       float* __restrict__ y2,
                       float* __restrict__ loss_slot) {
    int u = blockIdx.x * blockDim.x + threadIdx.x;   // 0..8191
    if (u == 0) *loss_slot = 0.0f;

    if (u < 64 * 2 * 64) {
        int lane  = u & 63;
        int kstep = (u >> 6) & 1;
        int mtile = u >> 7;
        int m  = mtile * 16 + (lane & 15);
        int d0 = kstep * 32 + ((lane >> 4) & 3) * 8;
        const float* src = cb + (size_t)m * DD + d0;
        half8 h, l;
#pragma unroll
        for (int j = 0; j < 8; ++j) {
            float x = -2.0f * src[j];
            _Float16 hi = (_Float16)x;
            _Float16 lo = (_Float16)((x - (float)hi) * LO_SCALE);
            h[j] = hi;
            l[j] = lo;
        }
        *(half8*)(ch + (size_t)u * 8) = h;
        *(half8*)(cl + (size_t)u * 8) = l;
    }

    if (u < MM) {
        const float4* c4 = (const float4*)(cb + (size_t)u * DD);
        float s = 0.f;
#pragma unroll
        for (int k = 0; k < 16; ++k) {
            float4 v = c4[k];
            s += v.x * v.x + v.y * v.y + v.z * v.z + v.w * v.w;
        }
        y2[u] = s;
    }
}

// ---------------------------------------------------------------------------
// Kernel 2 (main): fused distance + argmin + q_error + z_q + loss.
// 512 blocks x 512 threads (8 waves).  Block = 64 rows.
// B streamed global->LDS via global_load_lds (NO staging VGPRs -- rounds 4/5/6
// all died on register-held B-streams spilling to scratch), double-buffered
// 4-mtile 16KB chunks, one barrier per chunk:
//   barrier -> issue async loads chunk c+1 -> ds_read frags chunk c -> MFMA.
// Wave w: rh = w>>2 (2 ntiles = 32 rows), mi = w&3 (mtile-in-chunk; scans
// mt = 4c+mi, strictly increasing).  LDS ~60KB -> 2 blocks/CU; ~100 VGPRs.
// Noise tile is loaded AFTER the main loop into the same LDS as the B
// buffers (overlay union).
// Numerics: identical 6-MFMA sequence per (row,code), strict-< scan,
// idx-tie-broken merges -> bit-identical ind/z_q to all passing rounds.
// ---------------------------------------------------------------------------
__global__ __launch_bounds__(512) void k_main(const float* __restrict__ z,
                                              const float* __restrict__ noise,
                                              const _Float16* __restrict__ ch,
                                              const _Float16* __restrict__ cl,
                                              const float* __restrict__ y2,
                                              float* __restrict__ zq,
                                              float* __restrict__ ind_out,
                                              float* __restrict__ loss_slot) {
    __shared__ float zt[64][65];     // zt[row(hw)][d]
    __shared__ float y2s[MM];
    __shared__ float x2p[64][8];
    __shared__ float snorm[64];
    __shared__ float scale_s[64];
    __shared__ float bestv_s[4][64]; // [mi group][row]
    __shared__ int   besti_s[4][64];
    __shared__ float partials[512];
    __shared__ float sq[4];
    // B double buffer (2 x 16KB) UNION noise tile nt[64][65] (16.6KB, epilogue)
    __shared__ __align__(16) char ubuf[2 * 16384];

    half8* bufB8 = (half8*)ubuf;
    float (*nt)[65] = (float (*)[65])ubuf;

    const int t    = threadIdx.x;
    const int lane = t & 63;
    const int wv   = t >> 6;            // wave 0..7
    const int mi   = wv & 3;            // mtile-in-chunk
    const int rh   = wv >> 2;           // row half
    const int quad = lane >> 4;         // 0..3
    const int col  = lane & 15;         // 0..15
    const int blk  = blockIdx.x;        // 0..511
    const int b    = blk >> 4;
    const int hw0  = (blk & 15) << 6;

    const half8* ch8 = (const half8*)ch;
    const half8* cl8 = (const half8*)cl;

    // This wave's async-copy job: 2 segments of 64 half8 (1KB each) per chunk.
    // Segment s = 2*wv (+1); s<8 -> ch region, s>=8 -> cl region.
    // Chunk c source offset: +512c half8.  LDS dest: bufB8 + p*1024 + s*64.
    const half8* gseg = (wv < 4) ? (ch8 + wv * 128) : (cl8 + (wv - 4) * 128);
    half8* l0 = bufB8 + wv * 128;          // buffer 0 dest (wave-uniform)
    half8* l1 = bufB8 + 1024 + wv * 128;   // buffer 1 dest

    // issue chunk-0 async loads immediately (latency overlaps z staging)
    ASYNC16(gseg + lane,      l0);
    ASYNC16(gseg + 64 + lane, l0 + 64);

    const float* zbase = z + ((size_t)b << 16) + hw0;

    // ---- stage z tile (coalesced) + y2 ----
    for (int i = t; i < 64 * 64; i += 512) {
        int d = i >> 6, r = i & 63;
        zt[r][d] = zbase[(size_t)d * HW + r];
    }
    for (int i = t; i < MM; i += 512) y2s[i] = y2[i];
    __syncthreads();   // zt ready; vmcnt(0) drain -> chunk 0 resident in LDS

    // ---- x2 partials + resident A fragments (hi/lo fp16), 2 ntiles ----
    {
        int row = t & 63, seg = t >> 6;
        float s = 0.f;
#pragma unroll
        for (int j = 0; j < 8; ++j) {
            float v = zt[row][seg * 8 + j];
            s = __builtin_fmaf(v, v, s);
        }
        x2p[row][seg] = s;
    }

    // A frag: A[m][k]: m=lane&15, k=(lane>>4)*8+j.
    half8 ah[2][2], al[2][2];
#pragma unroll
    for (int n2 = 0; n2 < 2; ++n2) {
        int row = rh * 32 + n2 * 16 + col;
#pragma unroll
        for (int ks = 0; ks < 2; ++ks) {
            int d0 = ks * 32 + quad * 8;
            half8 h, l;
#pragma unroll
            for (int j = 0; j < 8; ++j) {
                float x = zt[row][d0 + j];
                _Float16 hi = (_Float16)x;
                _Float16 lo = (_Float16)((x - (float)hi) * LO_SCALE);
                h[j] = hi;
                l[j] = lo;
            }
            ah[n2][ks] = h;
            al[n2][ks] = l;
        }
    }

    // ---- main loop: 16 chunks, async double-buffer, 1 barrier/chunk ----
    float best[8];
    int   bmt[8];
#pragma unroll
    for (int s = 0; s < 8; ++s) { best[s] = 1e30f; bmt[s] = 0; }

#pragma unroll 2
    for (int c = 0; c < 16; ++c) {
        const int p = c & 1;
        if (c) __syncthreads();   // chunk c loads done; buffer 1-p free

        if (c < 15) {             // issue async loads for chunk c+1
            const half8* gs = gseg + (c + 1) * 512;
            half8* ls = ((c + 1) & 1) ? l1 : l0;
            ASYNC16(gs + lane,      ls);
            ASYNC16(gs + 64 + lane, ls + 64);
        }

        // B frags for this wave's mtile from LDS
        const half8* bp = bufB8 + p * 1024;
        half8 bh0 = bp[(mi * 2 + 0) * 64 + lane];
        half8 bh1 = bp[(mi * 2 + 1) * 64 + lane];
        half8 bl0 = bp[512 + (mi * 2 + 0) * 64 + lane];
        half8 bl1 = bp[512 + (mi * 2 + 1) * 64 + lane];

        const int mt = c * 4 + mi;
        float y2v = y2s[(mt << 4) + col];
        floatx4 a1[2], a2[2];
#pragma unroll
        for (int n2 = 0; n2 < 2; ++n2) {
            floatx4 i1 = {y2v, y2v, y2v, y2v};
            floatx4 i2 = {0.f, 0.f, 0.f, 0.f};
            a1[n2] = i1;
            a2[n2] = i2;
        }
#pragma unroll
        for (int n2 = 0; n2 < 2; ++n2) {
            a1[n2] = MFMA16(ah[n2][0], bh0, a1[n2]);   // hi*hi (k 0..31)
            a2[n2] = MFMA16(al[n2][0], bh0, a2[n2]);   // lo*hi
            a2[n2] = MFMA16(ah[n2][0], bl0, a2[n2]);   // hi*lo
            a1[n2] = MFMA16(ah[n2][1], bh1, a1[n2]);   // hi*hi (k 32..63)
            a2[n2] = MFMA16(al[n2][1], bh1, a2[n2]);
            a2[n2] = MFMA16(ah[n2][1], bl1, a2[n2]);
        }
#pragma unroll
        for (int n2 = 0; n2 < 2; ++n2) {
#pragma unroll
            for (int r = 0; r < 4; ++r) {
                float v = __builtin_fmaf(a2[n2][r], LO_INV, a1[n2][r]);
                int s = n2 * 4 + r;
                bool cc = v < best[s];
                best[s] = cc ? v : best[s];
                bmt[s]  = cc ? mt : bmt[s];
            }
        }
    }
    __syncthreads();   // all waves done with bufB -> safe to overlay nt

    // ---- noise tile load into overlay + row norms (overlaps argmin VALU) ----
    {
        const float4* noise4 = (const float4*)noise;
        const size_t base4 = (size_t)blk * 1024;     // 4096 floats / 4
#pragma unroll
        for (int k = 0; k < 2; ++k) {
            int v = t + 512 * k;                     // float4 index [0,1024)
            float4 vv = noise4[base4 + v];
            int c  = v >> 4;
            int d0 = (v & 15) << 2;
            nt[d0 + 0][c] = vv.x;
            nt[d0 + 1][c] = vv.y;
            nt[d0 + 2][c] = vv.z;
            nt[d0 + 3][c] = vv.w;
            float p = vv.x * vv.x + vv.y * vv.y + vv.z * vv.z + vv.w * vv.w;
            p += __shfl_xor(p, 1);
            p += __shfl_xor(p, 2);
            p += __shfl_xor(p, 4);
            p += __shfl_xor(p, 8);
            if ((t & 15) == 0) snorm[c] = p;
        }
    }

    // ---- per-wave cross-lane argmin (16 lanes share a row), then LDS ----
#pragma unroll
    for (int n2 = 0; n2 < 2; ++n2) {
#pragma unroll
        for (int r = 0; r < 4; ++r) {
            int s = n2 * 4 + r;
            float v  = best[s];
            int  idx = bmt[s] * 16 + col;
#pragma unroll
            for (int mask = 1; mask <= 8; mask <<= 1) {
                float v2 = __shfl_xor(v, mask);
                int   i2 = __shfl_xor(idx, mask);
                if (v2 < v || (v2 == v && i2 < idx)) { v = v2; idx = i2; }
            }
            if (col == 0) {
                int rl = rh * 32 + n2 * 16 + quad * 4 + r;
                bestv_s[mi][rl] = v;
                besti_s[mi][rl] = idx;
            }
        }
    }
    __syncthreads();

    // ---- merge mi-groups; write ind; compute scale in LDS ----
    if (t < 64) {
        float bv = bestv_s[0][t];
        int   bi = besti_s[0][t];
#pragma unroll
        for (int w = 1; w < 4; ++w) {
            float v = bestv_s[w][t];
            int   ix = besti_s[w][t];
            if (v < bv || (v == bv && ix < bi)) { bv = v; bi = ix; }
        }
        float x2 = 0.f;
#pragma unroll
        for (int s = 0; s < 8; ++s) x2 += x2p[t][s];
        float dm = x2 + bv;
        int n = (blk << 6) + t;
        ind_out[n] = (float)bi;
        float nr = fmaxf(sqrtf(snorm[t]), 1e-9f);
        scale_s[t] = sqrtf(fmaxf(dm, 0.f)) / nr;
    }
    __syncthreads();

    // ---- z_q write (coalesced, z from LDS) + loss partials ----
    float acc = 0.f;
    const size_t obase = ((size_t)b << 16) + hw0;
#pragma unroll
    for (int it = 0; it < 8; ++it) {
        int flat = it * 512 + t;
        int d = flat >> 6;               // wave-uniform
        int c = t & 63;
        float v = zt[c][d] + nt[d][c] * scale_s[c];
        zq[obase + (size_t)d * HW + c] = v;
        acc += v;
    }

    partials[t] = acc;
    __syncthreads();
    if (t < 4) {
        float s = 0.f;
        for (int g = 0; g < 8; ++g)
            for (int j = 0; j < 16; ++j)
                s += partials[g * 64 + t * 16 + j];
        sq[t] = s * s;
    }
    __syncthreads();
    if (t == 0) {
        float contrib = (sq[0] + sq[1] + sq[2] + sq[3]) * (1.0f / 33554432.0f);
        atomicAdd(loss_slot, contrib);
    }
}

// ---------------------------------------------------------------------------
extern "C" void kernel_launch(void* const* d_in, const int* in_sizes, int n_in,
                              void* d_out, int out_size, void* d_ws, size_t ws_size,
                              hipStream_t stream) {
    const float* z        = (const float*)d_in[0];   // (32,64,32,32)
    const float* codebook = (const float*)d_in[1];   // (1024,64)
    const float* noise    = (const float*)d_in[2];   // (32768,64)

    float* out      = (float*)d_out;
    float* zq_out   = out;                 // 2097152 floats
    float* loss_ptr = out + 2097152;       // 1 float
    float* ind_out  = out + 2097153;       // 32768 floats

    float* y2       = (float*)d_ws;             // 1024 floats
    _Float16* ch    = (_Float16*)(y2 + MM);     // 65536 halves (128KB)
    _Float16* cl    = ch + 65536;               // 65536 halves (128KB)

    k_prep<<<16,  512, 0, stream>>>(codebook, ch, cl, y2, loss_ptr);
    k_main<<<512, 512, 0, stream>>>(z, noise, ch, cl, y2,
                                    zq_out, ind_out, loss_ptr);
}